// Round 1
// baseline (1174.664 us; speedup 1.0000x reference)
//
#include <hip/hip_runtime.h>

#define IN_DIM 128
#define OUT_DIM 128
#define NUM_RELS 8

// out[z][n][o] = (bias ? bias[o] : 0) + sum_d x[n][d] * W[z][d][o]
// 256 threads/block; chunk = 16 nodes; each thread: 2 nodes x 4 outputs.
__global__ __launch_bounds__(256) void gemm128(
    const float* __restrict__ x, const float* __restrict__ W,
    const float* __restrict__ bias, float* __restrict__ out, int N)
{
    __shared__ float Ws[IN_DIM * OUT_DIM];   // 64 KB
    __shared__ float xs[16][IN_DIM];         // 8 KB

    const float* Wz = W + (size_t)blockIdx.z * IN_DIM * OUT_DIM;
    float* outz = out + (size_t)blockIdx.z * (size_t)N * OUT_DIM;

    // cooperative load of W tile into LDS (float4)
    {
        const float4* s4 = (const float4*)Wz;
        float4* d4 = (float4*)Ws;
        for (int i = threadIdx.x; i < IN_DIM * OUT_DIM / 4; i += 256)
            d4[i] = s4[i];
    }

    const int tid = threadIdx.x;
    const int nl = (tid >> 5) * 2;        // 0,2,...,14
    const int og = (tid & 31) * 4;        // 0,4,...,124

    float4 b4 = make_float4(0.f, 0.f, 0.f, 0.f);
    if (bias) b4 = *(const float4*)&bias[og];

    const int nchunks = (N + 15) / 16;
    for (int chunk = blockIdx.x; chunk < nchunks; chunk += gridDim.x) {
        const int n0 = chunk * 16;
        const int rows = min(16, N - n0);
        __syncthreads();  // xs reuse + first-iter W visibility
        {
            const float4* xsrc = (const float4*)(x + (size_t)n0 * IN_DIM);
            float4* xdst = (float4*)&xs[0][0];
            const int n4 = rows * (IN_DIM / 4);
            for (int i = tid; i < n4; i += 256) xdst[i] = xsrc[i];
        }
        __syncthreads();

        if (nl < rows) {
            float a00 = 0.f, a01 = 0.f, a02 = 0.f, a03 = 0.f;
            float a10 = 0.f, a11 = 0.f, a12 = 0.f, a13 = 0.f;
            #pragma unroll 8
            for (int d = 0; d < IN_DIM; ++d) {
                const float4 w4 = *(const float4*)&Ws[d * OUT_DIM + og];
                const float xa = xs[nl][d];
                const float xb = xs[nl + 1][d];
                a00 += xa * w4.x; a01 += xa * w4.y; a02 += xa * w4.z; a03 += xa * w4.w;
                a10 += xb * w4.x; a11 += xb * w4.y; a12 += xb * w4.z; a13 += xb * w4.w;
            }
            float4 r0 = make_float4(a00 + b4.x, a01 + b4.y, a02 + b4.z, a03 + b4.w);
            *(float4*)&outz[(size_t)(n0 + nl) * OUT_DIM + og] = r0;
            if (nl + 1 < rows) {
                float4 r1 = make_float4(a10 + b4.x, a11 + b4.y, a12 + b4.z, a13 + b4.w);
                *(float4*)&outz[(size_t)(n0 + nl + 1) * OUT_DIM + og] = r1;
            }
        }
    }
}

// out[dst[e]] += hr[et[e]][src[e]]  (32 lanes per edge, float4 each)
__global__ __launch_bounds__(256) void scatter_add(
    const float* __restrict__ hr, const int* __restrict__ src,
    const int* __restrict__ dst, const int* __restrict__ et,
    float* __restrict__ out, int E, int N)
{
    long t = (long)blockIdx.x * blockDim.x + threadIdx.x;
    long e = t >> 5;
    int lane = (int)(t & 31);
    if (e >= E) return;
    int s = src[e], d = dst[e], r = et[e];
    const float4 v = *(const float4*)(hr + ((long)r * N + s) * OUT_DIM + lane * 4);
    float* o = out + (long)d * OUT_DIM + lane * 4;
    atomicAdd(o + 0, v.x);
    atomicAdd(o + 1, v.y);
    atomicAdd(o + 2, v.z);
    atomicAdd(o + 3, v.w);
}

// per-relation variant: h is [N][128] for relation rel only
__global__ __launch_bounds__(256) void scatter_rel(
    const float* __restrict__ h, const int* __restrict__ src,
    const int* __restrict__ dst, const int* __restrict__ et, int rel,
    float* __restrict__ out, int E, int N)
{
    long t = (long)blockIdx.x * blockDim.x + threadIdx.x;
    long e = t >> 5;
    int lane = (int)(t & 31);
    if (e >= E) return;
    if (et[e] != rel) return;
    int s = src[e], d = dst[e];
    const float4 v = *(const float4*)(h + (long)s * OUT_DIM + lane * 4);
    float* o = out + (long)d * OUT_DIM + lane * 4;
    atomicAdd(o + 0, v.x);
    atomicAdd(o + 1, v.y);
    atomicAdd(o + 2, v.z);
    atomicAdd(o + 3, v.w);
}

// no-workspace fallback: one 64-lane wave per edge, direct x[src] @ W[et]
__global__ __launch_bounds__(256) void edge_direct(
    const float* __restrict__ x, const float* __restrict__ W,
    const int* __restrict__ src, const int* __restrict__ dst,
    const int* __restrict__ et, float* __restrict__ out, int E)
{
    long t = (long)blockIdx.x * blockDim.x + threadIdx.x;
    long e = t >> 6;
    int lane = (int)(t & 63);
    if (e >= E) return;
    int s = src[e], d = dst[e], r = et[e];
    const float* xr = x + (long)s * IN_DIM;
    float2 xv = *(const float2*)(xr + lane * 2);
    const float* Wr = W + (long)r * IN_DIM * OUT_DIM;
    const int o0 = lane * 2;
    float a0 = 0.f, a1 = 0.f;
    #pragma unroll 8
    for (int dd = 0; dd < 64; ++dd) {
        float xa = __shfl(xv.x, dd);
        float xb = __shfl(xv.y, dd);
        a0 += xa * Wr[(2 * dd) * OUT_DIM + o0]     + xb * Wr[(2 * dd + 1) * OUT_DIM + o0];
        a1 += xa * Wr[(2 * dd) * OUT_DIM + o0 + 1] + xb * Wr[(2 * dd + 1) * OUT_DIM + o0 + 1];
    }
    atomicAdd(out + (long)d * OUT_DIM + o0, a0);
    atomicAdd(out + (long)d * OUT_DIM + o0 + 1, a1);
}

__global__ __launch_bounds__(256) void relu_k(float* __restrict__ out, long n4)
{
    long i = (long)blockIdx.x * blockDim.x + threadIdx.x;
    if (i >= n4) return;
    float4 v = ((float4*)out)[i];
    v.x = fmaxf(v.x, 0.f); v.y = fmaxf(v.y, 0.f);
    v.z = fmaxf(v.z, 0.f); v.w = fmaxf(v.w, 0.f);
    ((float4*)out)[i] = v;
}

extern "C" void kernel_launch(void* const* d_in, const int* in_sizes, int n_in,
                              void* d_out, int out_size, void* d_ws, size_t ws_size,
                              hipStream_t stream)
{
    const float* x      = (const float*)d_in[0];
    const float* weight = (const float*)d_in[1];
    const float* slw    = (const float*)d_in[2];
    const float* bias   = (const float*)d_in[3];
    const int*   ei     = (const int*)d_in[4];
    const int*   et     = (const int*)d_in[5];

    const int N = in_sizes[0] / IN_DIM;     // 50000
    const int E = in_sizes[5];              // 500000
    const int* src = ei;
    const int* dstp = ei + E;

    float* out = (float*)d_out;
    float* ws  = (float*)d_ws;

    // K1: out = x @ self_loop_weight + bias (fully initializes out)
    gemm128<<<dim3(512, 1, 1), 256, 0, stream>>>(x, slw, bias, out, N);

    const size_t need_full = (size_t)NUM_RELS * N * OUT_DIM * sizeof(float);
    const size_t need_one  = (size_t)N * OUT_DIM * sizeof(float);

    if (ws_size >= need_full) {
        // hr[r] = x @ W[r] for all relations at once
        gemm128<<<dim3(64, 1, NUM_RELS), 256, 0, stream>>>(x, weight, nullptr, ws, N);
        long nt = (long)E * 32;
        scatter_add<<<dim3((nt + 255) / 256), 256, 0, stream>>>(ws, src, dstp, et, out, E, N);
    } else if (ws_size >= need_one) {
        for (int r = 0; r < NUM_RELS; ++r) {
            gemm128<<<dim3(256, 1, 1), 256, 0, stream>>>(
                x, weight + (size_t)r * IN_DIM * OUT_DIM, nullptr, ws, N);
            long nt = (long)E * 32;
            scatter_rel<<<dim3((nt + 255) / 256), 256, 0, stream>>>(ws, src, dstp, et, r, out, E, N);
        }
    } else {
        long nt = (long)E * 64;
        edge_direct<<<dim3((nt + 255) / 256), 256, 0, stream>>>(x, weight, src, dstp, et, out, E);
    }

    long n4 = (long)N * OUT_DIM / 4;
    relu_k<<<dim3((n4 + 255) / 256), 256, 0, stream>>>(out, n4);
}

// Round 2
// 538.151 us; speedup vs baseline: 2.1828x; 2.1828x over previous
//
#include <hip/hip_runtime.h>

#define IN_DIM 128
#define OUT_DIM 128
#define NUM_RELS 8
#define SCAN_THREADS 1024

// out[z][n][o] = (bias ? bias[o] : 0) + sum_d x[n][d] * W[z][d][o]
__global__ __launch_bounds__(256) void gemm128(
    const float* __restrict__ x, const float* __restrict__ W,
    const float* __restrict__ bias, float* __restrict__ out, int N)
{
    __shared__ float Ws[IN_DIM * OUT_DIM];   // 64 KB
    __shared__ float xs[16][IN_DIM];         // 8 KB

    const float* Wz = W + (size_t)blockIdx.z * IN_DIM * OUT_DIM;
    float* outz = out + (size_t)blockIdx.z * (size_t)N * OUT_DIM;

    {
        const float4* s4 = (const float4*)Wz;
        float4* d4 = (float4*)Ws;
        for (int i = threadIdx.x; i < IN_DIM * OUT_DIM / 4; i += 256)
            d4[i] = s4[i];
    }

    const int tid = threadIdx.x;
    const int nl = (tid >> 5) * 2;
    const int og = (tid & 31) * 4;

    float4 b4 = make_float4(0.f, 0.f, 0.f, 0.f);
    if (bias) b4 = *(const float4*)&bias[og];

    const int nchunks = (N + 15) / 16;
    for (int chunk = blockIdx.x; chunk < nchunks; chunk += gridDim.x) {
        const int n0 = chunk * 16;
        const int rows = min(16, N - n0);
        __syncthreads();
        {
            const float4* xsrc = (const float4*)(x + (size_t)n0 * IN_DIM);
            float4* xdst = (float4*)&xs[0][0];
            const int n4 = rows * (IN_DIM / 4);
            for (int i = tid; i < n4; i += 256) xdst[i] = xsrc[i];
        }
        __syncthreads();

        if (nl < rows) {
            float a00 = 0.f, a01 = 0.f, a02 = 0.f, a03 = 0.f;
            float a10 = 0.f, a11 = 0.f, a12 = 0.f, a13 = 0.f;
            #pragma unroll 8
            for (int d = 0; d < IN_DIM; ++d) {
                const float4 w4 = *(const float4*)&Ws[d * OUT_DIM + og];
                const float xa = xs[nl][d];
                const float xb = xs[nl + 1][d];
                a00 += xa * w4.x; a01 += xa * w4.y; a02 += xa * w4.z; a03 += xa * w4.w;
                a10 += xb * w4.x; a11 += xb * w4.y; a12 += xb * w4.z; a13 += xb * w4.w;
            }
            float4 r0 = make_float4(a00 + b4.x, a01 + b4.y, a02 + b4.z, a03 + b4.w);
            *(float4*)&outz[(size_t)(n0 + nl) * OUT_DIM + og] = r0;
            if (nl + 1 < rows) {
                float4 r1 = make_float4(a10 + b4.x, a11 + b4.y, a12 + b4.z, a13 + b4.w);
                *(float4*)&outz[(size_t)(n0 + nl + 1) * OUT_DIM + og] = r1;
            }
        }
    }
}

// ---------- CSR build ----------
__global__ __launch_bounds__(256) void k_zero(int* __restrict__ p, int n)
{
    int i = blockIdx.x * blockDim.x + threadIdx.x;
    if (i < n) p[i] = 0;
}

__global__ __launch_bounds__(256) void k_hist(
    const int* __restrict__ dst, int* __restrict__ deg, int E)
{
    int e = blockIdx.x * blockDim.x + threadIdx.x;
    if (e < E) atomicAdd(&deg[dst[e]], 1);
}

// single-block exclusive scan: deg[0..n) -> row_ptr[0..n], cursor[0..n)
// NOTE: deg may alias cursor — deg[i] is read into a temp before cursor[i] write.
__global__ __launch_bounds__(SCAN_THREADS) void k_scan(
    const int* __restrict__ deg, int* __restrict__ row_ptr,
    int* __restrict__ cursor, int n)
{
    __shared__ int sdata[SCAN_THREADS];
    const int t = threadIdx.x;
    const int chunk = (n + SCAN_THREADS - 1) / SCAN_THREADS;
    const int lo = t * chunk;
    const int hi = min(lo + chunk, n);

    int part = 0;
    for (int i = lo; i < hi; ++i) part += deg[i];
    sdata[t] = part;
    __syncthreads();
    for (int off = 1; off < SCAN_THREADS; off <<= 1) {
        int v = (t >= off) ? sdata[t - off] : 0;
        __syncthreads();
        sdata[t] += v;
        __syncthreads();
    }
    int run = sdata[t] - part;
    for (int i = lo; i < hi; ++i) {
        int d = deg[i];          // read before aliased write
        row_ptr[i] = run;
        cursor[i] = run;
        run += d;
    }
    if (t == 0) row_ptr[n] = sdata[SCAN_THREADS - 1];
}

__global__ __launch_bounds__(256) void k_fill(
    const int* __restrict__ src, const int* __restrict__ dst,
    const int* __restrict__ et, int* __restrict__ cursor,
    int* __restrict__ packed, int E)
{
    int e = blockIdx.x * blockDim.x + threadIdx.x;
    if (e >= E) return;
    int pos = atomicAdd(&cursor[dst[e]], 1);
    packed[pos] = (et[e] << 17) | src[e];
}

// pull-based aggregate: out[n] = relu(out[n] + sum_{incoming e} hr[et][src])
__global__ __launch_bounds__(256) void gather_csr(
    const float* __restrict__ hr, const int* __restrict__ row_ptr,
    const int* __restrict__ packed, float* __restrict__ out, int Nnodes, int N)
{
    int g = blockIdx.x * 8 + (threadIdx.x >> 5);
    int lane = threadIdx.x & 31;
    if (g >= Nnodes) return;
    const int beg = row_ptr[g];
    const int end = row_ptr[g + 1];
    float* op = out + (size_t)g * OUT_DIM + lane * 4;
    float4 acc = *(float4*)op;
    for (int k = beg; k < end; ++k) {
        int p = packed[k];
        int s = p & 0x1FFFF;
        int r = p >> 17;
        const float4 v = *(const float4*)&hr[((size_t)r * N + s) * OUT_DIM + lane * 4];
        acc.x += v.x; acc.y += v.y; acc.z += v.z; acc.w += v.w;
    }
    acc.x = fmaxf(acc.x, 0.f); acc.y = fmaxf(acc.y, 0.f);
    acc.z = fmaxf(acc.z, 0.f); acc.w = fmaxf(acc.w, 0.f);
    *(float4*)op = acc;
}

// ---------- fallbacks (small workspace) ----------
__global__ __launch_bounds__(256) void scatter_add(
    const float* __restrict__ hr, const int* __restrict__ src,
    const int* __restrict__ dst, const int* __restrict__ et,
    float* __restrict__ out, int E, int N)
{
    long t = (long)blockIdx.x * blockDim.x + threadIdx.x;
    long e = t >> 5;
    int lane = (int)(t & 31);
    if (e >= E) return;
    int s = src[e], d = dst[e], r = et[e];
    const float4 v = *(const float4*)(hr + ((long)r * N + s) * OUT_DIM + lane * 4);
    float* o = out + (long)d * OUT_DIM + lane * 4;
    atomicAdd(o + 0, v.x);
    atomicAdd(o + 1, v.y);
    atomicAdd(o + 2, v.z);
    atomicAdd(o + 3, v.w);
}

__global__ __launch_bounds__(256) void edge_direct(
    const float* __restrict__ x, const float* __restrict__ W,
    const int* __restrict__ src, const int* __restrict__ dst,
    const int* __restrict__ et, float* __restrict__ out, int E)
{
    long t = (long)blockIdx.x * blockDim.x + threadIdx.x;
    long e = t >> 6;
    int lane = (int)(t & 63);
    if (e >= E) return;
    int s = src[e], d = dst[e], r = et[e];
    const float* xr = x + (long)s * IN_DIM;
    float2 xv = *(const float2*)(xr + lane * 2);
    const float* Wr = W + (long)r * IN_DIM * OUT_DIM;
    const int o0 = lane * 2;
    float a0 = 0.f, a1 = 0.f;
    #pragma unroll 8
    for (int dd = 0; dd < 64; ++dd) {
        float xa = __shfl(xv.x, dd);
        float xb = __shfl(xv.y, dd);
        a0 += xa * Wr[(2 * dd) * OUT_DIM + o0]     + xb * Wr[(2 * dd + 1) * OUT_DIM + o0];
        a1 += xa * Wr[(2 * dd) * OUT_DIM + o0 + 1] + xb * Wr[(2 * dd + 1) * OUT_DIM + o0 + 1];
    }
    atomicAdd(out + (long)d * OUT_DIM + o0, a0);
    atomicAdd(out + (long)d * OUT_DIM + o0 + 1, a1);
}

__global__ __launch_bounds__(256) void relu_k(float* __restrict__ out, long n4)
{
    long i = (long)blockIdx.x * blockDim.x + threadIdx.x;
    if (i >= n4) return;
    float4 v = ((float4*)out)[i];
    v.x = fmaxf(v.x, 0.f); v.y = fmaxf(v.y, 0.f);
    v.z = fmaxf(v.z, 0.f); v.w = fmaxf(v.w, 0.f);
    ((float4*)out)[i] = v;
}

extern "C" void kernel_launch(void* const* d_in, const int* in_sizes, int n_in,
                              void* d_out, int out_size, void* d_ws, size_t ws_size,
                              hipStream_t stream)
{
    const float* x      = (const float*)d_in[0];
    const float* weight = (const float*)d_in[1];
    const float* slw    = (const float*)d_in[2];
    const float* bias   = (const float*)d_in[3];
    const int*   ei     = (const int*)d_in[4];
    const int*   et     = (const int*)d_in[5];

    const int N = in_sizes[0] / IN_DIM;     // 50000
    const int E = in_sizes[5];              // 500000
    const int* src = ei;
    const int* dstp = ei + E;

    float* out = (float*)d_out;

    // K1: out = x @ self_loop_weight + bias
    gemm128<<<dim3(512, 1, 1), 256, 0, stream>>>(x, slw, bias, out, N);

    const size_t hr_elems   = (size_t)NUM_RELS * N * OUT_DIM;
    const size_t need_full  = hr_elems * sizeof(float);
    const size_t csr_bytes  = (size_t)(2 * N + 1 + E) * sizeof(int);

    if (ws_size >= need_full + csr_bytes && N <= (1 << 17)) {
        float* hr     = (float*)d_ws;
        int* row_ptr  = (int*)((char*)d_ws + need_full);   // N+1
        int* cursor   = row_ptr + (N + 1);                 // N
        int* packed   = cursor + N;                        // E

        gemm128<<<dim3(64, 1, NUM_RELS), 256, 0, stream>>>(x, weight, nullptr, hr, N);

        k_zero<<<dim3((N + 255) / 256), 256, 0, stream>>>(cursor, N);
        k_hist<<<dim3((E + 255) / 256), 256, 0, stream>>>(dstp, cursor, E);
        k_scan<<<dim3(1), SCAN_THREADS, 0, stream>>>(cursor, row_ptr, cursor, N);
        k_fill<<<dim3((E + 255) / 256), 256, 0, stream>>>(src, dstp, et, cursor, packed, E);

        gather_csr<<<dim3((N + 7) / 8), 256, 0, stream>>>(hr, row_ptr, packed, out, N, N);
    } else if (ws_size >= need_full) {
        float* hr = (float*)d_ws;
        gemm128<<<dim3(64, 1, NUM_RELS), 256, 0, stream>>>(x, weight, nullptr, hr, N);
        long nt = (long)E * 32;
        scatter_add<<<dim3((nt + 255) / 256), 256, 0, stream>>>(hr, src, dstp, et, out, E, N);
        long n4 = (long)N * OUT_DIM / 4;
        relu_k<<<dim3((n4 + 255) / 256), 256, 0, stream>>>(out, n4);
    } else {
        long nt = (long)E * 64;
        edge_direct<<<dim3((nt + 255) / 256), 256, 0, stream>>>(x, weight, src, dstp, et, out, E);
        long n4 = (long)N * OUT_DIM / 4;
        relu_k<<<dim3((n4 + 255) / 256), 256, 0, stream>>>(out, n4);
    }
}

// Round 3
// 358.194 us; speedup vs baseline: 3.2794x; 1.5024x over previous
//
#include <hip/hip_runtime.h>

#define IN_DIM 128
#define OUT_DIM 128
#define NUM_RELS 8
#define SCAN_THREADS 1024

typedef unsigned short u16;
typedef u16 u16x8 __attribute__((ext_vector_type(8)));
typedef u16 u16x4 __attribute__((ext_vector_type(4)));
typedef __bf16 bf16x8 __attribute__((ext_vector_type(8)));
typedef float f32x4 __attribute__((ext_vector_type(4)));

__device__ __forceinline__ u16 f2bf(float f) {
    unsigned u = __float_as_uint(f);
    u += 0x7FFF + ((u >> 16) & 1);      // RNE
    return (u16)(u >> 16);
}
__device__ __forceinline__ float bf2f(u16 h) {
    return __uint_as_float((unsigned)h << 16);
}

// ---------- fp32 -> bf16 conversion (n must be multiple of 4) ----------
__global__ __launch_bounds__(256) void k_f2bf(
    const float* __restrict__ in, u16* __restrict__ out, long n)
{
    long i = ((long)blockIdx.x * blockDim.x + threadIdx.x) * 4;
    if (i >= n) return;
    float4 v = *(const float4*)(in + i);
    u16x4 o;
    o[0] = f2bf(v.x); o[1] = f2bf(v.y); o[2] = f2bf(v.z); o[3] = f2bf(v.w);
    *(u16x4*)(out + i) = o;
}

// ---------- MFMA GEMM: hr[z] = xb @ Wb[z]  (z==8 adds bias) ----------
// grid (G, 1, 9), 256 threads (4 waves). 128x128 output tile per block-iter.
__global__ __launch_bounds__(256) void mfma_gemm(
    const u16* __restrict__ xb,    // [N][128] bf16
    const u16* __restrict__ Wb,    // [9][128][128] bf16, row-major [k][col]
    const float* __restrict__ bias,
    u16* __restrict__ hr,          // [9][N][128] bf16
    int N, int ntiles)
{
    __shared__ u16 Wt[128][136];   // Wt[col][k]  (transposed, padded)
    __shared__ u16 Xs[128][136];   // x tile / output staging (padded)

    const int tid  = threadIdx.x;
    const int z    = blockIdx.z;
    const int wv   = tid >> 6;
    const int lane = tid & 63;
    const int quad = lane >> 4;
    const int l    = lane & 15;
    const int m0   = wv * 32;

    // stage W[z] transposed into LDS (once per block)
    {
        const u16* Wz = Wb + (size_t)z * 128 * 128;
        for (int i = tid; i < 2048; i += 256) {
            int k  = i >> 4;
            int c0 = (i & 15) * 8;
            u16x8 w = *(const u16x8*)(Wz + k * 128 + c0);
            #pragma unroll
            for (int j = 0; j < 8; ++j) Wt[c0 + j][k] = w[j];
        }
    }

    // bias values for this lane's 8 column tiles (only for z==8)
    float bv[8];
    #pragma unroll
    for (int nt = 0; nt < 8; ++nt)
        bv[nt] = (z == 8) ? bias[nt * 16 + l] : 0.f;

    for (int tile = blockIdx.x; tile < ntiles; tile += gridDim.x) {
        const int n0 = tile * 128;
        __syncthreads();   // Wt ready (first iter) / prior readback done

        // stage x tile (zero-pad beyond N)
        for (int i = tid; i < 2048; i += 256) {
            int r  = i >> 4;
            int c0 = (i & 15) * 8;
            int gr = n0 + r;
            u16x8 v;
            if (gr < N) {
                v = *(const u16x8*)(xb + (size_t)gr * 128 + c0);
            } else {
                #pragma unroll
                for (int j = 0; j < 8; ++j) v[j] = 0;
            }
            *(u16x8*)&Xs[r][c0] = v;
        }
        __syncthreads();

        f32x4 acc[2][8] = {};
        #pragma unroll
        for (int kc = 0; kc < 4; ++kc) {
            const int kk = kc * 32 + quad * 8;
            bf16x8 a0 = __builtin_bit_cast(bf16x8, *(const u16x8*)&Xs[m0 + l][kk]);
            bf16x8 a1 = __builtin_bit_cast(bf16x8, *(const u16x8*)&Xs[m0 + 16 + l][kk]);
            #pragma unroll
            for (int nt = 0; nt < 8; ++nt) {
                bf16x8 b = __builtin_bit_cast(bf16x8, *(const u16x8*)&Wt[nt * 16 + l][kk]);
                acc[0][nt] = __builtin_amdgcn_mfma_f32_16x16x32_bf16(a0, b, acc[0][nt], 0, 0, 0);
                acc[1][nt] = __builtin_amdgcn_mfma_f32_16x16x32_bf16(a1, b, acc[1][nt], 0, 0, 0);
            }
        }

        __syncthreads();   // all waves done reading Xs
        // write accumulators (as bf16) into Xs for coalesced readback
        #pragma unroll
        for (int mt = 0; mt < 2; ++mt)
            #pragma unroll
            for (int nt = 0; nt < 8; ++nt) {
                const int col = nt * 16 + l;
                #pragma unroll
                for (int j = 0; j < 4; ++j) {
                    const int row = m0 + mt * 16 + quad * 4 + j;
                    Xs[row][col] = f2bf(acc[mt][nt][j] + bv[nt]);
                }
            }
        __syncthreads();

        // coalesced bf16 store
        u16* hrz = hr + ((size_t)z * N + n0) * 128;
        for (int i = tid; i < 2048; i += 256) {
            int r = i >> 4;
            if (n0 + r < N) {
                int c0 = (i & 15) * 8;
                *(u16x8*)(hrz + (size_t)r * 128 + c0) = *(const u16x8*)&Xs[r][c0];
            }
        }
    }
}

// ---------- CSR build ----------
__global__ __launch_bounds__(256) void k_zero(int* __restrict__ p, int n)
{
    int i = blockIdx.x * blockDim.x + threadIdx.x;
    if (i < n) p[i] = 0;
}

__global__ __launch_bounds__(256) void k_hist(
    const int* __restrict__ dst, int* __restrict__ deg, int E)
{
    int e = blockIdx.x * blockDim.x + threadIdx.x;
    if (e < E) atomicAdd(&deg[dst[e]], 1);
}

// single-block exclusive scan; deg may alias cursor (read temp before write)
__global__ __launch_bounds__(SCAN_THREADS) void k_scan(
    const int* __restrict__ deg, int* __restrict__ row_ptr,
    int* __restrict__ cursor, int n)
{
    __shared__ int sdata[SCAN_THREADS];
    const int t = threadIdx.x;
    const int chunk = (n + SCAN_THREADS - 1) / SCAN_THREADS;
    const int lo = t * chunk;
    const int hi = min(lo + chunk, n);

    int part = 0;
    for (int i = lo; i < hi; ++i) part += deg[i];
    sdata[t] = part;
    __syncthreads();
    for (int off = 1; off < SCAN_THREADS; off <<= 1) {
        int v = (t >= off) ? sdata[t - off] : 0;
        __syncthreads();
        sdata[t] += v;
        __syncthreads();
    }
    int run = sdata[t] - part;
    for (int i = lo; i < hi; ++i) {
        int d = deg[i];
        row_ptr[i] = run;
        cursor[i] = run;
        run += d;
    }
    if (t == 0) row_ptr[n] = sdata[SCAN_THREADS - 1];
}

__global__ __launch_bounds__(256) void k_fill(
    const int* __restrict__ src, const int* __restrict__ dst,
    const int* __restrict__ et, int* __restrict__ cursor,
    int* __restrict__ packed, int E)
{
    int e = blockIdx.x * blockDim.x + threadIdx.x;
    if (e >= E) return;
    int pos = atomicAdd(&cursor[dst[e]], 1);
    packed[pos] = (et[e] << 17) | src[e];
}

// ---------- pull-based aggregate (bf16 hr) ----------
__global__ __launch_bounds__(256) void gather_bf16(
    const u16* __restrict__ hr,      // [8][N][128] bf16
    const u16* __restrict__ hself,   // [N][128] bf16 (x@slw + bias)
    const int* __restrict__ row_ptr, const int* __restrict__ packed,
    float* __restrict__ out, int Nn, int N)
{
    int g = blockIdx.x * 8 + (threadIdx.x >> 5);
    int lane = threadIdx.x & 31;
    if (g >= Nn) return;
    const int beg = row_ptr[g];
    const int end = row_ptr[g + 1];

    u16x4 s = *(const u16x4*)(hself + (size_t)g * 128 + lane * 4);
    float a0 = bf2f(s[0]), a1 = bf2f(s[1]), a2 = bf2f(s[2]), a3 = bf2f(s[3]);

    for (int k = beg; k < end; ++k) {
        int p = packed[k];
        int sn = p & 0x1FFFF;
        int r  = p >> 17;
        u16x4 v = *(const u16x4*)(hr + ((size_t)r * N + sn) * 128 + lane * 4);
        a0 += bf2f(v[0]); a1 += bf2f(v[1]); a2 += bf2f(v[2]); a3 += bf2f(v[3]);
    }
    float4 o = make_float4(fmaxf(a0, 0.f), fmaxf(a1, 0.f),
                           fmaxf(a2, 0.f), fmaxf(a3, 0.f));
    *(float4*)(out + (size_t)g * 128 + lane * 4) = o;
}

// ---------- fp32 fallback kernels (small workspace) ----------
__global__ __launch_bounds__(256) void gemm128(
    const float* __restrict__ x, const float* __restrict__ W,
    const float* __restrict__ bias, float* __restrict__ out, int N)
{
    __shared__ float Ws[IN_DIM * OUT_DIM];
    __shared__ float xs[16][IN_DIM];

    const float* Wz = W + (size_t)blockIdx.z * IN_DIM * OUT_DIM;
    float* outz = out + (size_t)blockIdx.z * (size_t)N * OUT_DIM;

    {
        const float4* s4 = (const float4*)Wz;
        float4* d4 = (float4*)Ws;
        for (int i = threadIdx.x; i < IN_DIM * OUT_DIM / 4; i += 256)
            d4[i] = s4[i];
    }

    const int tid = threadIdx.x;
    const int nl = (tid >> 5) * 2;
    const int og = (tid & 31) * 4;

    float4 b4 = make_float4(0.f, 0.f, 0.f, 0.f);
    if (bias) b4 = *(const float4*)&bias[og];

    const int nchunks = (N + 15) / 16;
    for (int chunk = blockIdx.x; chunk < nchunks; chunk += gridDim.x) {
        const int n0 = chunk * 16;
        const int rows = min(16, N - n0);
        __syncthreads();
        {
            const float4* xsrc = (const float4*)(x + (size_t)n0 * IN_DIM);
            float4* xdst = (float4*)&xs[0][0];
            const int n4 = rows * (IN_DIM / 4);
            for (int i = tid; i < n4; i += 256) xdst[i] = xsrc[i];
        }
        __syncthreads();

        if (nl < rows) {
            float a00 = 0.f, a01 = 0.f, a02 = 0.f, a03 = 0.f;
            float a10 = 0.f, a11 = 0.f, a12 = 0.f, a13 = 0.f;
            #pragma unroll 8
            for (int d = 0; d < IN_DIM; ++d) {
                const float4 w4 = *(const float4*)&Ws[d * OUT_DIM + og];
                const float xa = xs[nl][d];
                const float xb = xs[nl + 1][d];
                a00 += xa * w4.x; a01 += xa * w4.y; a02 += xa * w4.z; a03 += xa * w4.w;
                a10 += xb * w4.x; a11 += xb * w4.y; a12 += xb * w4.z; a13 += xb * w4.w;
            }
            float4 r0 = make_float4(a00 + b4.x, a01 + b4.y, a02 + b4.z, a03 + b4.w);
            *(float4*)&outz[(size_t)(n0 + nl) * OUT_DIM + og] = r0;
            if (nl + 1 < rows) {
                float4 r1 = make_float4(a10 + b4.x, a11 + b4.y, a12 + b4.z, a13 + b4.w);
                *(float4*)&outz[(size_t)(n0 + nl + 1) * OUT_DIM + og] = r1;
            }
        }
    }
}

__global__ __launch_bounds__(256) void edge_direct(
    const float* __restrict__ x, const float* __restrict__ W,
    const int* __restrict__ src, const int* __restrict__ dst,
    const int* __restrict__ et, float* __restrict__ out, int E)
{
    long t = (long)blockIdx.x * blockDim.x + threadIdx.x;
    long e = t >> 6;
    int lane = (int)(t & 63);
    if (e >= E) return;
    int s = src[e], d = dst[e], r = et[e];
    const float* xr = x + (long)s * IN_DIM;
    float2 xv = *(const float2*)(xr + lane * 2);
    const float* Wr = W + (long)r * IN_DIM * OUT_DIM;
    const int o0 = lane * 2;
    float a0 = 0.f, a1 = 0.f;
    #pragma unroll 8
    for (int dd = 0; dd < 64; ++dd) {
        float xa = __shfl(xv.x, dd);
        float xb = __shfl(xv.y, dd);
        a0 += xa * Wr[(2 * dd) * OUT_DIM + o0]     + xb * Wr[(2 * dd + 1) * OUT_DIM + o0];
        a1 += xa * Wr[(2 * dd) * OUT_DIM + o0 + 1] + xb * Wr[(2 * dd + 1) * OUT_DIM + o0 + 1];
    }
    atomicAdd(out + (long)d * OUT_DIM + o0, a0);
    atomicAdd(out + (long)d * OUT_DIM + o0 + 1, a1);
}

__global__ __launch_bounds__(256) void relu_k(float* __restrict__ out, long n4)
{
    long i = (long)blockIdx.x * blockDim.x + threadIdx.x;
    if (i >= n4) return;
    float4 v = ((float4*)out)[i];
    v.x = fmaxf(v.x, 0.f); v.y = fmaxf(v.y, 0.f);
    v.z = fmaxf(v.z, 0.f); v.w = fmaxf(v.w, 0.f);
    ((float4*)out)[i] = v;
}

static inline size_t align256(size_t x) { return (x + 255) & ~(size_t)255; }

extern "C" void kernel_launch(void* const* d_in, const int* in_sizes, int n_in,
                              void* d_out, int out_size, void* d_ws, size_t ws_size,
                              hipStream_t stream)
{
    const float* x      = (const float*)d_in[0];
    const float* weight = (const float*)d_in[1];
    const float* slw    = (const float*)d_in[2];
    const float* bias   = (const float*)d_in[3];
    const int*   ei     = (const int*)d_in[4];
    const int*   et     = (const int*)d_in[5];

    const int N = in_sizes[0] / IN_DIM;
    const int E = in_sizes[5];
    const int* src  = ei;
    const int* dstp = ei + E;

    float* out = (float*)d_out;

    // workspace layout (bf16 path)
    size_t off = 0;
    const size_t xb_off   = off; off += align256((size_t)N * 128 * 2);
    const size_t wb_off   = off; off += align256((size_t)9 * 128 * 128 * 2);
    const size_t hr_off   = off; off += align256((size_t)9 * N * 128 * 2);
    const size_t rp_off   = off; off += align256((size_t)(N + 1) * 4);
    const size_t cur_off  = off; off += align256((size_t)N * 4);
    const size_t pk_off   = off; off += align256((size_t)E * 4);
    const size_t need_bf16 = off;

    if (ws_size >= need_bf16 && N <= (1 << 17)) {
        char* base  = (char*)d_ws;
        u16* xb     = (u16*)(base + xb_off);
        u16* Wbq    = (u16*)(base + wb_off);
        u16* hr     = (u16*)(base + hr_off);
        int* row_ptr = (int*)(base + rp_off);
        int* cursor  = (int*)(base + cur_off);
        int* packed  = (int*)(base + pk_off);

        // convert inputs to bf16
        long nx = (long)N * 128;
        k_f2bf<<<dim3((nx / 4 + 255) / 256), 256, 0, stream>>>(x, xb, nx);
        k_f2bf<<<dim3((NUM_RELS * 16384 / 4 + 255) / 256), 256, 0, stream>>>(
            weight, Wbq, NUM_RELS * 16384);
        k_f2bf<<<dim3((16384 / 4 + 255) / 256), 256, 0, stream>>>(
            slw, Wbq + NUM_RELS * 16384, 16384);

        // CSR build
        k_zero<<<dim3((N + 255) / 256), 256, 0, stream>>>(cursor, N);
        k_hist<<<dim3((E + 255) / 256), 256, 0, stream>>>(dstp, cursor, E);
        k_scan<<<dim3(1), SCAN_THREADS, 0, stream>>>(cursor, row_ptr, cursor, N);
        k_fill<<<dim3((E + 255) / 256), 256, 0, stream>>>(src, dstp, et, cursor, packed, E);

        // all 9 transforms via MFMA
        const int ntiles = (N + 127) / 128;
        mfma_gemm<<<dim3(64, 1, 9), 256, 0, stream>>>(xb, Wbq, bias, hr, N, ntiles);

        // aggregate + self + relu -> out
        gather_bf16<<<dim3((N + 7) / 8), 256, 0, stream>>>(
            hr, hr + (size_t)8 * N * 128, row_ptr, packed, out, N, N);
    } else if (ws_size >= (size_t)NUM_RELS * N * 128 * 4) {
        // fp32 fallback: hr in ws, atomic scatter
        float* hrf = (float*)d_ws;
        gemm128<<<dim3(512, 1, 1), 256, 0, stream>>>(x, slw, bias, out, N);
        gemm128<<<dim3(64, 1, NUM_RELS), 256, 0, stream>>>(x, weight, nullptr, hrf, N);
        // simple scatter (atomics)
        long nt = (long)E * 64;
        edge_direct<<<dim3((nt + 255) / 256), 256, 0, stream>>>(x, weight, src, dstp, et, out, E);
        long n4 = (long)N * OUT_DIM / 4;
        relu_k<<<dim3((n4 + 255) / 256), 256, 0, stream>>>(out, n4);
    } else {
        gemm128<<<dim3(512, 1, 1), 256, 0, stream>>>(x, slw, bias, out, N);
        long nt = (long)E * 64;
        edge_direct<<<dim3((nt + 255) / 256), 256, 0, stream>>>(x, weight, src, dstp, et, out, E);
        long n4 = (long)N * OUT_DIM / 4;
        relu_k<<<dim3((n4 + 255) / 256), 256, 0, stream>>>(out, n4);
    }
}

// Round 4
// 264.047 us; speedup vs baseline: 4.4487x; 1.3566x over previous
//
#include <hip/hip_runtime.h>

#define IN_DIM 128
#define OUT_DIM 128
#define NUM_RELS 8
#define SCAN_ELEMS 2048   // per block, 256 thr x 8

typedef unsigned short u16;
typedef u16 u16x8 __attribute__((ext_vector_type(8)));
typedef u16 u16x4 __attribute__((ext_vector_type(4)));
typedef __bf16 bf16x8 __attribute__((ext_vector_type(8)));
typedef float f32x4 __attribute__((ext_vector_type(4)));

__device__ __forceinline__ u16 f2bf(float f) {
    unsigned u = __float_as_uint(f);
    u += 0x7FFF + ((u >> 16) & 1);      // RNE
    return (u16)(u >> 16);
}
__device__ __forceinline__ float bf2f(u16 h) {
    return __uint_as_float((unsigned)h << 16);
}

// ---------- fp32 -> bf16 conversion (n multiple of 4) ----------
__global__ __launch_bounds__(256) void k_f2bf(
    const float* __restrict__ in, u16* __restrict__ out, long n)
{
    long i = ((long)blockIdx.x * blockDim.x + threadIdx.x) * 4;
    if (i >= n) return;
    float4 v = *(const float4*)(in + i);
    u16x4 o;
    o[0] = f2bf(v.x); o[1] = f2bf(v.y); o[2] = f2bf(v.z); o[3] = f2bf(v.w);
    *(u16x4*)(out + i) = o;
}

// ---------- MFMA GEMM: hr[z] = xb @ Wb[z]  (z==8 adds bias) ----------
__global__ __launch_bounds__(256) void mfma_gemm(
    const u16* __restrict__ xb,    // [N][128] bf16
    const u16* __restrict__ Wb,    // [9][128][128] bf16
    const float* __restrict__ bias,
    u16* __restrict__ hr,          // [9][N][128] bf16
    int N, int ntiles)
{
    __shared__ u16 Wt[128][136];   // Wt[col][k]
    __shared__ u16 Xs[128][136];

    const int tid  = threadIdx.x;
    const int z    = blockIdx.z;
    const int wv   = tid >> 6;
    const int lane = tid & 63;
    const int quad = lane >> 4;
    const int l    = lane & 15;
    const int m0   = wv * 32;

    {
        const u16* Wz = Wb + (size_t)z * 128 * 128;
        for (int i = tid; i < 2048; i += 256) {
            int k  = i >> 4;
            int c0 = (i & 15) * 8;
            u16x8 w = *(const u16x8*)(Wz + k * 128 + c0);
            #pragma unroll
            for (int j = 0; j < 8; ++j) Wt[c0 + j][k] = w[j];
        }
    }

    float bv[8];
    #pragma unroll
    for (int nt = 0; nt < 8; ++nt)
        bv[nt] = (z == 8) ? bias[nt * 16 + l] : 0.f;

    for (int tile = blockIdx.x; tile < ntiles; tile += gridDim.x) {
        const int n0 = tile * 128;
        __syncthreads();

        for (int i = tid; i < 2048; i += 256) {
            int r  = i >> 4;
            int c0 = (i & 15) * 8;
            int gr = n0 + r;
            u16x8 v;
            if (gr < N) {
                v = *(const u16x8*)(xb + (size_t)gr * 128 + c0);
            } else {
                #pragma unroll
                for (int j = 0; j < 8; ++j) v[j] = 0;
            }
            *(u16x8*)&Xs[r][c0] = v;
        }
        __syncthreads();

        f32x4 acc[2][8] = {};
        #pragma unroll
        for (int kc = 0; kc < 4; ++kc) {
            const int kk = kc * 32 + quad * 8;
            bf16x8 a0 = __builtin_bit_cast(bf16x8, *(const u16x8*)&Xs[m0 + l][kk]);
            bf16x8 a1 = __builtin_bit_cast(bf16x8, *(const u16x8*)&Xs[m0 + 16 + l][kk]);
            #pragma unroll
            for (int nt = 0; nt < 8; ++nt) {
                bf16x8 b = __builtin_bit_cast(bf16x8, *(const u16x8*)&Wt[nt * 16 + l][kk]);
                acc[0][nt] = __builtin_amdgcn_mfma_f32_16x16x32_bf16(a0, b, acc[0][nt], 0, 0, 0);
                acc[1][nt] = __builtin_amdgcn_mfma_f32_16x16x32_bf16(a1, b, acc[1][nt], 0, 0, 0);
            }
        }

        __syncthreads();
        #pragma unroll
        for (int mt = 0; mt < 2; ++mt)
            #pragma unroll
            for (int nt = 0; nt < 8; ++nt) {
                const int col = nt * 16 + l;
                #pragma unroll
                for (int j = 0; j < 4; ++j) {
                    const int row = m0 + mt * 16 + quad * 4 + j;
                    Xs[row][col] = f2bf(acc[mt][nt][j] + bv[nt]);
                }
            }
        __syncthreads();

        u16* hrz = hr + ((size_t)z * N + n0) * 128;
        for (int i = tid; i < 2048; i += 256) {
            int r = i >> 4;
            if (n0 + r < N) {
                int c0 = (i & 15) * 8;
                *(u16x8*)(hrz + (size_t)r * 128 + c0) = *(const u16x8*)&Xs[r][c0];
            }
        }
    }
}

// ---------- CSR build ----------
__global__ __launch_bounds__(256) void k_zero(int* __restrict__ p, int n)
{
    int i = blockIdx.x * blockDim.x + threadIdx.x;
    if (i < n) p[i] = 0;
}

__global__ __launch_bounds__(256) void k_hist(
    const int* __restrict__ dst, int* __restrict__ deg, int E)
{
    int e = blockIdx.x * blockDim.x + threadIdx.x;
    if (e < E) atomicAdd(&deg[dst[e]], 1);
}

// phase 1: per-block scan. local[i] = exclusive prefix within block, bsum[b] = block total
__global__ __launch_bounds__(256) void k_scan1(
    const int* __restrict__ deg, int* __restrict__ local,
    int* __restrict__ bsum, int n)
{
    __shared__ int s[256];
    const int t = threadIdx.x;
    const int base = blockIdx.x * SCAN_ELEMS + t * 8;
    int v[8];
    int sum = 0;
    #pragma unroll
    for (int j = 0; j < 8; ++j) {
        int i = base + j;
        v[j] = (i < n) ? deg[i] : 0;
        sum += v[j];
    }
    s[t] = sum;
    __syncthreads();
    #pragma unroll
    for (int off = 1; off < 256; off <<= 1) {
        int y = (t >= off) ? s[t - off] : 0;
        __syncthreads();
        s[t] += y;
        __syncthreads();
    }
    int run = s[t] - sum;   // exclusive prefix of this thread
    #pragma unroll
    for (int j = 0; j < 8; ++j) {
        int i = base + j;
        if (i < n) local[i] = run;
        run += v[j];
    }
    if (t == 255) bsum[blockIdx.x] = s[255];
}

// phase 2: scan block totals (B <= 256), write grand total to row_ptr[n]
__global__ __launch_bounds__(256) void k_scan2(
    int* __restrict__ bsum, int* __restrict__ row_ptr, int B, int n)
{
    __shared__ int s[256];
    const int t = threadIdx.x;
    int v = (t < B) ? bsum[t] : 0;
    s[t] = v;
    __syncthreads();
    #pragma unroll
    for (int off = 1; off < 256; off <<= 1) {
        int y = (t >= off) ? s[t - off] : 0;
        __syncthreads();
        s[t] += y;
        __syncthreads();
    }
    if (t < B) bsum[t] = s[t] - v;          // exclusive
    if (t == 255) row_ptr[n] = s[255];      // grand total
}

// phase 3: row_ptr[i] = local[i] + bsum[block]; cursor[i] = same
__global__ __launch_bounds__(256) void k_scan3(
    int* __restrict__ row_ptr, const int* __restrict__ bsum,
    int* __restrict__ cursor, int n)
{
    const int t = threadIdx.x;
    const int base = blockIdx.x * SCAN_ELEMS + t * 8;
    const int off = bsum[blockIdx.x];
    #pragma unroll
    for (int j = 0; j < 8; ++j) {
        int i = base + j;
        if (i < n) {
            int val = row_ptr[i] + off;
            row_ptr[i] = val;
            cursor[i] = val;
        }
    }
}

__global__ __launch_bounds__(256) void k_fill(
    const int* __restrict__ src, const int* __restrict__ dst,
    const int* __restrict__ et, int* __restrict__ cursor,
    int* __restrict__ packed, int E)
{
    int e = blockIdx.x * blockDim.x + threadIdx.x;
    if (e >= E) return;
    int pos = atomicAdd(&cursor[dst[e]], 1);
    packed[pos] = (et[e] << 17) | src[e];
}

// ---------- pull-based aggregate (bf16 hr) ----------
__global__ __launch_bounds__(256) void gather_bf16(
    const u16* __restrict__ hr,      // [8][N][128] bf16
    const u16* __restrict__ hself,   // [N][128] bf16 (x@slw + bias)
    const int* __restrict__ row_ptr, const int* __restrict__ packed,
    float* __restrict__ out, int Nn, int N)
{
    int g = blockIdx.x * 8 + (threadIdx.x >> 5);
    int lane = threadIdx.x & 31;
    if (g >= Nn) return;
    const int beg = row_ptr[g];
    const int end = row_ptr[g + 1];

    u16x4 s = *(const u16x4*)(hself + (size_t)g * 128 + lane * 4);
    float a0 = bf2f(s[0]), a1 = bf2f(s[1]), a2 = bf2f(s[2]), a3 = bf2f(s[3]);

    for (int k = beg; k < end; ++k) {
        int p = packed[k];
        int sn = p & 0x1FFFF;
        int r  = p >> 17;
        u16x4 v = *(const u16x4*)(hr + ((size_t)r * N + sn) * 128 + lane * 4);
        a0 += bf2f(v[0]); a1 += bf2f(v[1]); a2 += bf2f(v[2]); a3 += bf2f(v[3]);
    }
    float4 o = make_float4(fmaxf(a0, 0.f), fmaxf(a1, 0.f),
                           fmaxf(a2, 0.f), fmaxf(a3, 0.f));
    *(float4*)(out + (size_t)g * 128 + lane * 4) = o;
}

// ---------- fp32 fallback kernels ----------
__global__ __launch_bounds__(256) void gemm128(
    const float* __restrict__ x, const float* __restrict__ W,
    const float* __restrict__ bias, float* __restrict__ out, int N)
{
    __shared__ float Ws[IN_DIM * OUT_DIM];
    __shared__ float xs[16][IN_DIM];

    const float* Wz = W + (size_t)blockIdx.z * IN_DIM * OUT_DIM;
    float* outz = out + (size_t)blockIdx.z * (size_t)N * OUT_DIM;

    {
        const float4* s4 = (const float4*)Wz;
        float4* d4 = (float4*)Ws;
        for (int i = threadIdx.x; i < IN_DIM * OUT_DIM / 4; i += 256)
            d4[i] = s4[i];
    }

    const int tid = threadIdx.x;
    const int nl = (tid >> 5) * 2;
    const int og = (tid & 31) * 4;

    float4 b4 = make_float4(0.f, 0.f, 0.f, 0.f);
    if (bias) b4 = *(const float4*)&bias[og];

    const int nchunks = (N + 15) / 16;
    for (int chunk = blockIdx.x; chunk < nchunks; chunk += gridDim.x) {
        const int n0 = chunk * 16;
        const int rows = min(16, N - n0);
        __syncthreads();
        {
            const float4* xsrc = (const float4*)(x + (size_t)n0 * IN_DIM);
            float4* xdst = (float4*)&xs[0][0];
            const int n4 = rows * (IN_DIM / 4);
            for (int i = tid; i < n4; i += 256) xdst[i] = xsrc[i];
        }
        __syncthreads();

        if (nl < rows) {
            float a00 = 0.f, a01 = 0.f, a02 = 0.f, a03 = 0.f;
            float a10 = 0.f, a11 = 0.f, a12 = 0.f, a13 = 0.f;
            #pragma unroll 8
            for (int d = 0; d < IN_DIM; ++d) {
                const float4 w4 = *(const float4*)&Ws[d * OUT_DIM + og];
                const float xa = xs[nl][d];
                const float xb = xs[nl + 1][d];
                a00 += xa * w4.x; a01 += xa * w4.y; a02 += xa * w4.z; a03 += xa * w4.w;
                a10 += xb * w4.x; a11 += xb * w4.y; a12 += xb * w4.z; a13 += xb * w4.w;
            }
            float4 r0 = make_float4(a00 + b4.x, a01 + b4.y, a02 + b4.z, a03 + b4.w);
            *(float4*)&outz[(size_t)(n0 + nl) * OUT_DIM + og] = r0;
            if (nl + 1 < rows) {
                float4 r1 = make_float4(a10 + b4.x, a11 + b4.y, a12 + b4.z, a13 + b4.w);
                *(float4*)&outz[(size_t)(n0 + nl + 1) * OUT_DIM + og] = r1;
            }
        }
    }
}

__global__ __launch_bounds__(256) void edge_direct(
    const float* __restrict__ x, const float* __restrict__ W,
    const int* __restrict__ src, const int* __restrict__ dst,
    const int* __restrict__ et, float* __restrict__ out, int E)
{
    long t = (long)blockIdx.x * blockDim.x + threadIdx.x;
    long e = t >> 6;
    int lane = (int)(t & 63);
    if (e >= E) return;
    int s = src[e], d = dst[e], r = et[e];
    const float* xr = x + (long)s * IN_DIM;
    float2 xv = *(const float2*)(xr + lane * 2);
    const float* Wr = W + (long)r * IN_DIM * OUT_DIM;
    const int o0 = lane * 2;
    float a0 = 0.f, a1 = 0.f;
    #pragma unroll 8
    for (int dd = 0; dd < 64; ++dd) {
        float xa = __shfl(xv.x, dd);
        float xb = __shfl(xv.y, dd);
        a0 += xa * Wr[(2 * dd) * OUT_DIM + o0]     + xb * Wr[(2 * dd + 1) * OUT_DIM + o0];
        a1 += xa * Wr[(2 * dd) * OUT_DIM + o0 + 1] + xb * Wr[(2 * dd + 1) * OUT_DIM + o0 + 1];
    }
    atomicAdd(out + (long)d * OUT_DIM + o0, a0);
    atomicAdd(out + (long)d * OUT_DIM + o0 + 1, a1);
}

__global__ __launch_bounds__(256) void relu_k(float* __restrict__ out, long n4)
{
    long i = (long)blockIdx.x * blockDim.x + threadIdx.x;
    if (i >= n4) return;
    float4 v = ((float4*)out)[i];
    v.x = fmaxf(v.x, 0.f); v.y = fmaxf(v.y, 0.f);
    v.z = fmaxf(v.z, 0.f); v.w = fmaxf(v.w, 0.f);
    ((float4*)out)[i] = v;
}

static inline size_t align256(size_t x) { return (x + 255) & ~(size_t)255; }

extern "C" void kernel_launch(void* const* d_in, const int* in_sizes, int n_in,
                              void* d_out, int out_size, void* d_ws, size_t ws_size,
                              hipStream_t stream)
{
    const float* x      = (const float*)d_in[0];
    const float* weight = (const float*)d_in[1];
    const float* slw    = (const float*)d_in[2];
    const float* bias   = (const float*)d_in[3];
    const int*   ei     = (const int*)d_in[4];
    const int*   et     = (const int*)d_in[5];

    const int N = in_sizes[0] / IN_DIM;
    const int E = in_sizes[5];
    const int* src  = ei;
    const int* dstp = ei + E;

    float* out = (float*)d_out;

    // workspace layout (bf16 path)
    size_t off = 0;
    const size_t xb_off   = off; off += align256((size_t)N * 128 * 2);
    const size_t wb_off   = off; off += align256((size_t)9 * 128 * 128 * 2);
    const size_t hr_off   = off; off += align256((size_t)9 * N * 128 * 2);
    const size_t rp_off   = off; off += align256((size_t)(N + 1) * 4);
    const size_t cur_off  = off; off += align256((size_t)N * 4);
    const size_t pk_off   = off; off += align256((size_t)E * 4);
    const size_t bs_off   = off; off += align256(256 * 4);
    const size_t need_bf16 = off;

    const int scanB = (N + SCAN_ELEMS - 1) / SCAN_ELEMS;

    if (ws_size >= need_bf16 && N <= (1 << 17) && scanB <= 256) {
        char* base   = (char*)d_ws;
        u16* xb      = (u16*)(base + xb_off);
        u16* Wbq     = (u16*)(base + wb_off);
        u16* hr      = (u16*)(base + hr_off);
        int* row_ptr = (int*)(base + rp_off);
        int* cursor  = (int*)(base + cur_off);
        int* packed  = (int*)(base + pk_off);
        int* bsum    = (int*)(base + bs_off);

        // convert inputs to bf16
        long nx = (long)N * 128;
        k_f2bf<<<dim3((nx / 4 + 255) / 256), 256, 0, stream>>>(x, xb, nx);
        k_f2bf<<<dim3((NUM_RELS * 16384 / 4 + 255) / 256), 256, 0, stream>>>(
            weight, Wbq, NUM_RELS * 16384);
        k_f2bf<<<dim3((16384 / 4 + 255) / 256), 256, 0, stream>>>(
            slw, Wbq + NUM_RELS * 16384, 16384);

        // CSR build (deg lives in cursor)
        k_zero<<<dim3((N + 255) / 256), 256, 0, stream>>>(cursor, N);
        k_hist<<<dim3((E + 255) / 256), 256, 0, stream>>>(dstp, cursor, E);
        k_scan1<<<dim3(scanB), 256, 0, stream>>>(cursor, row_ptr, bsum, N);
        k_scan2<<<dim3(1), 256, 0, stream>>>(bsum, row_ptr, scanB, N);
        k_scan3<<<dim3(scanB), 256, 0, stream>>>(row_ptr, bsum, cursor, N);
        k_fill<<<dim3((E + 255) / 256), 256, 0, stream>>>(src, dstp, et, cursor, packed, E);

        // all 9 transforms via MFMA
        const int ntiles = (N + 127) / 128;
        mfma_gemm<<<dim3(64, 1, 9), 256, 0, stream>>>(xb, Wbq, bias, hr, N, ntiles);

        // aggregate + self + relu -> out
        gather_bf16<<<dim3((N + 7) / 8), 256, 0, stream>>>(
            hr, hr + (size_t)8 * N * 128, row_ptr, packed, out, N, N);
    } else if (ws_size >= (size_t)NUM_RELS * N * 128 * 4) {
        float* hrf = (float*)d_ws;
        (void)hrf;
        gemm128<<<dim3(512, 1, 1), 256, 0, stream>>>(x, slw, bias, out, N);
        long nt = (long)E * 64;
        edge_direct<<<dim3((nt + 255) / 256), 256, 0, stream>>>(x, weight, src, dstp, et, out, E);
        long n4 = (long)N * OUT_DIM / 4;
        relu_k<<<dim3((n4 + 255) / 256), 256, 0, stream>>>(out, n4);
    } else {
        gemm128<<<dim3(512, 1, 1), 256, 0, stream>>>(x, slw, bias, out, N);
        long nt = (long)E * 64;
        edge_direct<<<dim3((nt + 255) / 256), 256, 0, stream>>>(x, weight, src, dstp, et, out, E);
        long n4 = (long)N * OUT_DIM / 4;
        relu_k<<<dim3((n4 + 255) / 256), 256, 0, stream>>>(out, n4);
    }
}

// Round 5
// 225.675 us; speedup vs baseline: 5.2051x; 1.1700x over previous
//
#include <hip/hip_runtime.h>

#define IN_DIM 128
#define OUT_DIM 128
#define NUM_RELS 8
#define SCAN_ELEMS 2048   // per block, 256 thr x 8

typedef unsigned short u16;
typedef u16 u16x8 __attribute__((ext_vector_type(8)));
typedef u16 u16x4 __attribute__((ext_vector_type(4)));
typedef __bf16 bf16x8 __attribute__((ext_vector_type(8)));
typedef float f32x4 __attribute__((ext_vector_type(4)));

__device__ __forceinline__ u16 f2bf(float f) {
    unsigned u = __float_as_uint(f);
    u += 0x7FFF + ((u >> 16) & 1);      // RNE
    return (u16)(u >> 16);
}
__device__ __forceinline__ float bf2f(u16 h) {
    return __uint_as_float((unsigned)h << 16);
}

// ---------- fp32 -> bf16 conversion (n multiple of 4) ----------
__global__ __launch_bounds__(256) void k_f2bf(
    const float* __restrict__ in, u16* __restrict__ out, long n)
{
    long i = ((long)blockIdx.x * blockDim.x + threadIdx.x) * 4;
    if (i >= n) return;
    float4 v = *(const float4*)(in + i);
    u16x4 o;
    o[0] = f2bf(v.x); o[1] = f2bf(v.y); o[2] = f2bf(v.z); o[3] = f2bf(v.w);
    *(u16x4*)(out + i) = o;
}

// cast weight (8*16384) and slw (16384) into one [9][128][128] bf16 buffer
__global__ __launch_bounds__(256) void k_f2bf_w(
    const float* __restrict__ weight, const float* __restrict__ slw,
    u16* __restrict__ out)
{
    int i = (blockIdx.x * blockDim.x + threadIdx.x) * 4;
    if (i >= 9 * 16384) return;
    const float* src = (i < 8 * 16384) ? (weight + i) : (slw + (i - 8 * 16384));
    float4 v = *(const float4*)src;
    u16x4 o;
    o[0] = f2bf(v.x); o[1] = f2bf(v.y); o[2] = f2bf(v.z); o[3] = f2bf(v.w);
    *(u16x4*)(out + i) = o;
}

// ---------- MFMA GEMM v2: hr[z] = xb @ Wb[z]  (z==8 adds bias) ----------
// grid (56,1,9) x 256 thr (4 waves). Each wave: 64 rows x 64 cols.
// B-frags in registers (loaded once per block), A-frags direct from global,
// wave-private LDS epilogue slab. No __syncthreads.
__global__ __launch_bounds__(256, 2) void mfma_gemm2(
    const u16* __restrict__ xb,    // [N][128] bf16
    const u16* __restrict__ Wb,    // [9][128][128] bf16
    const float* __restrict__ bias,
    u16* __restrict__ hr,          // [9][N][128] bf16
    int N, int ntiles)
{
    __shared__ u16 slab[4][16 * 68];   // per-wave epilogue staging (stride 68)

    const int tid   = threadIdx.x;
    const int z     = blockIdx.z;
    const int wv    = tid >> 6;
    const int lane  = tid & 63;
    const int q     = lane >> 4;       // quad
    const int l     = lane & 15;
    const int mbase = (wv >> 1) * 64;  // row slab within 128-tile
    const int cbase = (wv & 1) * 64;   // col slab

    const u16* Wz = Wb + (size_t)z * 128 * 128;

    // B-frags: B[nt][kc] lane holds W[k = kc*32 + q*8 + j][cbase + nt*16 + l]
    u16x8 Bf[4][4];
    #pragma unroll
    for (int nt = 0; nt < 4; ++nt) {
        const int col = cbase + nt * 16 + l;
        #pragma unroll
        for (int kc = 0; kc < 4; ++kc) {
            const int k0 = kc * 32 + q * 8;
            #pragma unroll
            for (int j = 0; j < 8; ++j)
                Bf[nt][kc][j] = Wz[(k0 + j) * 128 + col];
        }
    }

    // bias per column tile (z==8 only)
    float bv[4];
    #pragma unroll
    for (int nt = 0; nt < 4; ++nt)
        bv[nt] = (z == 8) ? bias[cbase + nt * 16 + l] : 0.f;

    u16* slabw = &slab[wv][0];

    for (int tile = blockIdx.x; tile < ntiles; tile += gridDim.x) {
        const int n0 = tile * 128;

        f32x4 acc[4][4] = {};

        #pragma unroll
        for (int kc = 0; kc < 4; ++kc) {
            const int k0 = kc * 32 + q * 8;
            u16x8 a[4];
            #pragma unroll
            for (int mt = 0; mt < 4; ++mt) {
                const int row = n0 + mbase + mt * 16 + l;
                u16x8 v = {};
                if (row < N) v = *(const u16x8*)(xb + (size_t)row * 128 + k0);
                a[mt] = v;
            }
            #pragma unroll
            for (int nt = 0; nt < 4; ++nt) {
                bf16x8 b = __builtin_bit_cast(bf16x8, Bf[nt][kc]);
                #pragma unroll
                for (int mt = 0; mt < 4; ++mt) {
                    acc[mt][nt] = __builtin_amdgcn_mfma_f32_16x16x32_bf16(
                        __builtin_bit_cast(bf16x8, a[mt]), b, acc[mt][nt], 0, 0, 0);
                }
            }
        }

        // epilogue: per m-tile, stage 16x64 slab in LDS, read back coalesced
        u16* hrz = hr + ((size_t)z * N) * 128;
        #pragma unroll
        for (int mt = 0; mt < 4; ++mt) {
            #pragma unroll
            for (int nt = 0; nt < 4; ++nt) {
                const int col = nt * 16 + l;
                #pragma unroll
                for (int j = 0; j < 4; ++j) {
                    slabw[(q * 4 + j) * 68 + col] = f2bf(acc[mt][nt][j] + bv[nt]);
                }
            }
            // wave-internal: ds ordering enforced by compiler waitcnt
            const int srow = lane >> 3;          // 0..7
            const int scol = (lane & 7) * 8;     // 0..56
            #pragma unroll
            for (int h = 0; h < 2; ++h) {
                const int r = h * 8 + srow;
                const int grow = n0 + mbase + mt * 16 + r;
                if (grow < N) {
                    u16x8 v = *(const u16x8*)&slabw[r * 68 + scol];
                    *(u16x8*)(hrz + (size_t)grow * 128 + cbase + scol) = v;
                }
            }
        }
    }
}

// ---------- CSR build ----------
__global__ __launch_bounds__(256) void k_zero(int* __restrict__ p, int n)
{
    int i = blockIdx.x * blockDim.x + threadIdx.x;
    if (i < n) p[i] = 0;
}

__global__ __launch_bounds__(256) void k_hist(
    const int* __restrict__ dst, int* __restrict__ deg, int E)
{
    int e = blockIdx.x * blockDim.x + threadIdx.x;
    if (e < E) atomicAdd(&deg[dst[e]], 1);
}

__global__ __launch_bounds__(256) void k_scan1(
    const int* __restrict__ deg, int* __restrict__ local,
    int* __restrict__ bsum, int n)
{
    __shared__ int s[256];
    const int t = threadIdx.x;
    const int base = blockIdx.x * SCAN_ELEMS + t * 8;
    int v[8];
    int sum = 0;
    #pragma unroll
    for (int j = 0; j < 8; ++j) {
        int i = base + j;
        v[j] = (i < n) ? deg[i] : 0;
        sum += v[j];
    }
    s[t] = sum;
    __syncthreads();
    #pragma unroll
    for (int off = 1; off < 256; off <<= 1) {
        int y = (t >= off) ? s[t - off] : 0;
        __syncthreads();
        s[t] += y;
        __syncthreads();
    }
    int run = s[t] - sum;
    #pragma unroll
    for (int j = 0; j < 8; ++j) {
        int i = base + j;
        if (i < n) local[i] = run;
        run += v[j];
    }
    if (t == 255) bsum[blockIdx.x] = s[255];
}

__global__ __launch_bounds__(256) void k_scan2(
    int* __restrict__ bsum, int* __restrict__ row_ptr, int B, int n)
{
    __shared__ int s[256];
    const int t = threadIdx.x;
    int v = (t < B) ? bsum[t] : 0;
    s[t] = v;
    __syncthreads();
    #pragma unroll
    for (int off = 1; off < 256; off <<= 1) {
        int y = (t >= off) ? s[t - off] : 0;
        __syncthreads();
        s[t] += y;
        __syncthreads();
    }
    if (t < B) bsum[t] = s[t] - v;
    if (t == 255) row_ptr[n] = s[255];
}

__global__ __launch_bounds__(256) void k_scan3(
    int* __restrict__ row_ptr, const int* __restrict__ bsum,
    int* __restrict__ cursor, int n)
{
    const int t = threadIdx.x;
    const int base = blockIdx.x * SCAN_ELEMS + t * 8;
    const int off = bsum[blockIdx.x];
    #pragma unroll
    for (int j = 0; j < 8; ++j) {
        int i = base + j;
        if (i < n) {
            int val = row_ptr[i] + off;
            row_ptr[i] = val;
            cursor[i] = val;
        }
    }
}

__global__ __launch_bounds__(256) void k_fill(
    const int* __restrict__ src, const int* __restrict__ dst,
    const int* __restrict__ et, int* __restrict__ cursor,
    int* __restrict__ packed, int E)
{
    int e = blockIdx.x * blockDim.x + threadIdx.x;
    if (e >= E) return;
    int pos = atomicAdd(&cursor[dst[e]], 1);
    packed[pos] = (et[e] << 17) | src[e];
}

// ---------- pull-based aggregate (bf16 hr) ----------
__global__ __launch_bounds__(256) void gather_bf16(
    const u16* __restrict__ hr,      // [8][N][128] bf16
    const u16* __restrict__ hself,   // [N][128] bf16 (x@slw + bias)
    const int* __restrict__ row_ptr, const int* __restrict__ packed,
    float* __restrict__ out, int Nn, int N)
{
    int g = blockIdx.x * 8 + (threadIdx.x >> 5);
    int lane = threadIdx.x & 31;
    if (g >= Nn) return;
    const int beg = row_ptr[g];
    const int end = row_ptr[g + 1];

    u16x4 s = *(const u16x4*)(hself + (size_t)g * 128 + lane * 4);
    float a0 = bf2f(s[0]), a1 = bf2f(s[1]), a2 = bf2f(s[2]), a3 = bf2f(s[3]);

    for (int k = beg; k < end; ++k) {
        int p = packed[k];
        int sn = p & 0x1FFFF;
        int r  = p >> 17;
        u16x4 v = *(const u16x4*)(hr + ((size_t)r * N + sn) * 128 + lane * 4);
        a0 += bf2f(v[0]); a1 += bf2f(v[1]); a2 += bf2f(v[2]); a3 += bf2f(v[3]);
    }
    float4 o = make_float4(fmaxf(a0, 0.f), fmaxf(a1, 0.f),
                           fmaxf(a2, 0.f), fmaxf(a3, 0.f));
    *(float4*)(out + (size_t)g * 128 + lane * 4) = o;
}

// ---------- fp32 fallback kernels ----------
__global__ __launch_bounds__(256) void gemm128(
    const float* __restrict__ x, const float* __restrict__ W,
    const float* __restrict__ bias, float* __restrict__ out, int N)
{
    __shared__ float Ws[IN_DIM * OUT_DIM];
    __shared__ float xs[16][IN_DIM];

    const float* Wz = W + (size_t)blockIdx.z * IN_DIM * OUT_DIM;
    float* outz = out + (size_t)blockIdx.z * (size_t)N * OUT_DIM;

    {
        const float4* s4 = (const float4*)Wz;
        float4* d4 = (float4*)Ws;
        for (int i = threadIdx.x; i < IN_DIM * OUT_DIM / 4; i += 256)
            d4[i] = s4[i];
    }

    const int tid = threadIdx.x;
    const int nl = (tid >> 5) * 2;
    const int og = (tid & 31) * 4;

    float4 b4 = make_float4(0.f, 0.f, 0.f, 0.f);
    if (bias) b4 = *(const float4*)&bias[og];

    const int nchunks = (N + 15) / 16;
    for (int chunk = blockIdx.x; chunk < nchunks; chunk += gridDim.x) {
        const int n0 = chunk * 16;
        const int rows = min(16, N - n0);
        __syncthreads();
        {
            const float4* xsrc = (const float4*)(x + (size_t)n0 * IN_DIM);
            float4* xdst = (float4*)&xs[0][0];
            const int n4 = rows * (IN_DIM / 4);
            for (int i = tid; i < n4; i += 256) xdst[i] = xsrc[i];
        }
        __syncthreads();

        if (nl < rows) {
            float a00 = 0.f, a01 = 0.f, a02 = 0.f, a03 = 0.f;
            float a10 = 0.f, a11 = 0.f, a12 = 0.f, a13 = 0.f;
            #pragma unroll 8
            for (int d = 0; d < IN_DIM; ++d) {
                const float4 w4 = *(const float4*)&Ws[d * OUT_DIM + og];
                const float xa = xs[nl][d];
                const float xb = xs[nl + 1][d];
                a00 += xa * w4.x; a01 += xa * w4.y; a02 += xa * w4.z; a03 += xa * w4.w;
                a10 += xb * w4.x; a11 += xb * w4.y; a12 += xb * w4.z; a13 += xb * w4.w;
            }
            float4 r0 = make_float4(a00 + b4.x, a01 + b4.y, a02 + b4.z, a03 + b4.w);
            *(float4*)&outz[(size_t)(n0 + nl) * OUT_DIM + og] = r0;
            if (nl + 1 < rows) {
                float4 r1 = make_float4(a10 + b4.x, a11 + b4.y, a12 + b4.z, a13 + b4.w);
                *(float4*)&outz[(size_t)(n0 + nl + 1) * OUT_DIM + og] = r1;
            }
        }
    }
}

__global__ __launch_bounds__(256) void edge_direct(
    const float* __restrict__ x, const float* __restrict__ W,
    const int* __restrict__ src, const int* __restrict__ dst,
    const int* __restrict__ et, float* __restrict__ out, int E)
{
    long t = (long)blockIdx.x * blockDim.x + threadIdx.x;
    long e = t >> 6;
    int lane = (int)(t & 63);
    if (e >= E) return;
    int s = src[e], d = dst[e], r = et[e];
    const float* xr = x + (long)s * IN_DIM;
    float2 xv = *(const float2*)(xr + lane * 2);
    const float* Wr = W + (long)r * IN_DIM * OUT_DIM;
    const int o0 = lane * 2;
    float a0 = 0.f, a1 = 0.f;
    #pragma unroll 8
    for (int dd = 0; dd < 64; ++dd) {
        float xa = __shfl(xv.x, dd);
        float xb = __shfl(xv.y, dd);
        a0 += xa * Wr[(2 * dd) * OUT_DIM + o0]     + xb * Wr[(2 * dd + 1) * OUT_DIM + o0];
        a1 += xa * Wr[(2 * dd) * OUT_DIM + o0 + 1] + xb * Wr[(2 * dd + 1) * OUT_DIM + o0 + 1];
    }
    atomicAdd(out + (long)d * OUT_DIM + o0, a0);
    atomicAdd(out + (long)d * OUT_DIM + o0 + 1, a1);
}

__global__ __launch_bounds__(256) void relu_k(float* __restrict__ out, long n4)
{
    long i = (long)blockIdx.x * blockDim.x + threadIdx.x;
    if (i >= n4) return;
    float4 v = ((float4*)out)[i];
    v.x = fmaxf(v.x, 0.f); v.y = fmaxf(v.y, 0.f);
    v.z = fmaxf(v.z, 0.f); v.w = fmaxf(v.w, 0.f);
    ((float4*)out)[i] = v;
}

static inline size_t align256(size_t x) { return (x + 255) & ~(size_t)255; }

extern "C" void kernel_launch(void* const* d_in, const int* in_sizes, int n_in,
                              void* d_out, int out_size, void* d_ws, size_t ws_size,
                              hipStream_t stream)
{
    const float* x      = (const float*)d_in[0];
    const float* weight = (const float*)d_in[1];
    const float* slw    = (const float*)d_in[2];
    const float* bias   = (const float*)d_in[3];
    const int*   ei     = (const int*)d_in[4];
    const int*   et     = (const int*)d_in[5];

    const int N = in_sizes[0] / IN_DIM;
    const int E = in_sizes[5];
    const int* src  = ei;
    const int* dstp = ei + E;

    float* out = (float*)d_out;

    // workspace layout (bf16 path)
    size_t off = 0;
    const size_t xb_off   = off; off += align256((size_t)N * 128 * 2);
    const size_t wb_off   = off; off += align256((size_t)9 * 128 * 128 * 2);
    const size_t hr_off   = off; off += align256((size_t)9 * N * 128 * 2);
    const size_t rp_off   = off; off += align256((size_t)(N + 1) * 4);
    const size_t cur_off  = off; off += align256((size_t)N * 4);
    const size_t pk_off   = off; off += align256((size_t)E * 4);
    const size_t bs_off   = off; off += align256(256 * 4);
    const size_t need_bf16 = off;

    const int scanB = (N + SCAN_ELEMS - 1) / SCAN_ELEMS;

    if (ws_size >= need_bf16 && N <= (1 << 17) && scanB <= 256) {
        char* base   = (char*)d_ws;
        u16* xb      = (u16*)(base + xb_off);
        u16* Wbq     = (u16*)(base + wb_off);
        u16* hr      = (u16*)(base + hr_off);
        int* row_ptr = (int*)(base + rp_off);
        int* cursor  = (int*)(base + cur_off);
        int* packed  = (int*)(base + pk_off);
        int* bsum    = (int*)(base + bs_off);

        // convert inputs to bf16
        long nx = (long)N * 128;
        k_f2bf<<<dim3((nx / 4 + 255) / 256), 256, 0, stream>>>(x, xb, nx);
        k_f2bf_w<<<dim3((9 * 16384 / 4 + 255) / 256), 256, 0, stream>>>(weight, slw, Wbq);

        // CSR build (deg lives in cursor)
        k_zero<<<dim3((N + 255) / 256), 256, 0, stream>>>(cursor, N);
        k_hist<<<dim3((E + 255) / 256), 256, 0, stream>>>(dstp, cursor, E);
        k_scan1<<<dim3(scanB), 256, 0, stream>>>(cursor, row_ptr, bsum, N);
        k_scan2<<<dim3(1), 256, 0, stream>>>(bsum, row_ptr, scanB, N);
        k_scan3<<<dim3(scanB), 256, 0, stream>>>(row_ptr, bsum, cursor, N);
        k_fill<<<dim3((E + 255) / 256), 256, 0, stream>>>(src, dstp, et, cursor, packed, E);

        // all 9 transforms via MFMA (B-in-regs, A-from-global, no barriers)
        const int ntiles = (N + 127) / 128;
        mfma_gemm2<<<dim3(56, 1, 9), 256, 0, stream>>>(xb, Wbq, bias, hr, N, ntiles);

        // aggregate + self + relu -> out
        gather_bf16<<<dim3((N + 7) / 8), 256, 0, stream>>>(
            hr, hr + (size_t)8 * N * 128, row_ptr, packed, out, N, N);
    } else if (ws_size >= (size_t)NUM_RELS * N * 128 * 4) {
        gemm128<<<dim3(512, 1, 1), 256, 0, stream>>>(x, slw, bias, out, N);
        long nt = (long)E * 64;
        edge_direct<<<dim3((nt + 255) / 256), 256, 0, stream>>>(x, weight, src, dstp, et, out, E);
        long n4 = (long)N * OUT_DIM / 4;
        relu_k<<<dim3((n4 + 255) / 256), 256, 0, stream>>>(out, n4);
    } else {
        gemm128<<<dim3(512, 1, 1), 256, 0, stream>>>(x, slw, bias, out, N);
        long nt = (long)E * 64;
        edge_direct<<<dim3((nt + 255) / 256), 256, 0, stream>>>(x, weight, src, dstp, et, out, E);
        long n4 = (long)N * OUT_DIM / 4;
        relu_k<<<dim3((n4 + 255) / 256), 256, 0, stream>>>(out, n4);
    }
}